// Round 8
// baseline (248.854 us; speedup 1.0000x reference)
//
#include <hip/hip_runtime.h>
#include <hip/hip_bf16.h>

// SwitchLinear: B=4,S=2048,D_IN=1024,D_OUT=1024,E=8
// Established contract: ALL inputs fp32, OUTPUT fp32 (out_size=8388609 floats:
// 8192x1024 dense out + aux scalar). ws >= 262400 B. Routing = argmax of fp32
// gate logits; out[t,:] = x[t]@We[top1]^T + be[top1]; aux = mean((mean_gate*E)^2).
// Value GEMM: bf16 MFMA (input-rounding error ~1e-3 << 6.4e-2 threshold).
// Gate logits MUST stay fp32: bf16 logit noise (~2e-3) would flip ~dozens of
// argmax decisions -> O(1) output errors.
//
// v9: revert v8's failed single-kernel fusion (grid.sync did NOT make plain
// loads coherent across XCD L2s: absmax 3.19 = unwritten tokens). Back to
// the verified v7 gemm (76us, 0 bank conflicts). New:
//  (1) gate ILP: j-outer / 4-tokens-unrolled-inner (Wg loaded once per j,
//      16 independent FMA chains; v3 ran tokens serially with unroll 1).
//  (2) route merged into gate via LAST-BLOCK pattern with proper device-scope
//      acquire/release atomics (CUB-style: threadfence -> fetch_add(ACQ_REL,
//      AGENT) -> acquire fence -> route). 2 launches total; gemm keeps its
//      kernel-boundary coherence.
// Decision round: if total ~135-150, gate was the hidden ~50-70us; if ~175,
// gate exonerated -> residual is harness overhead.

#define NTOK 8192
#define DIN  1024
#define DOUT 1024
#define NE   8

typedef unsigned short u16;
typedef unsigned int   u32;
typedef unsigned long long u64;
typedef short  bf16x8 __attribute__((ext_vector_type(8)));
typedef float  f32x4  __attribute__((ext_vector_type(4)));

__device__ __forceinline__ u16 f2bf(float f) {
    __hip_bfloat16 h = __float2bfloat16(f);   // RNE
    return *(u16*)&h;
}

// ws layout: [0,32) counts[8] | [32,36) done | [256, 262400) tok_list[8][8192]
// First 32KB of tok_list region doubles as gate-record staging (512 x 64B);
// the route phase loads all records before scattering over them.

// ---------------------------------------------------------------------------
// gate+route: 512 blocks x 256 thr; block = 16 tokens, wave = 4 tokens
// (fully unrolled, Wg amortized). Records -> stage; last block to finish
// (device-scope atomic ticket) runs the scan+scatter route and aux.
// ---------------------------------------------------------------------------
__global__ __launch_bounds__(256) void gate_route_kernel(
    const float* __restrict__ x, const float* __restrict__ Wg,
    const float* __restrict__ bg, int* __restrict__ counts,
    int* __restrict__ done, int* __restrict__ tok_list,
    u32* __restrict__ stage, float* __restrict__ out)
{
    __shared__ union {
        struct { int am[16]; float mg[4][NE]; } gt;
        struct { int cnt[512][9]; float mgred[4][NE]; } r;   // 18.6 KB
    } sm;
    __shared__ int isLast;

    const int tid  = threadIdx.x;
    const int bid  = blockIdx.x;
    const int wave = tid >> 6;
    const int lane = tid & 63;
    const int g    = lane >> 3;          // expert this 8-lane group computes
    const int sub  = lane & 7;

    // ---------------- gate: 4 tokens per wave, ILP-unrolled ----------------
    {
        const float* wr = Wg + g * DIN + 4 * sub;
        const float* xr[4];
        #pragma unroll
        for (int it = 0; it < 4; ++it)
            xr[it] = x + (size_t)(bid * 16 + wave * 4 + it) * DIN + 4 * sub;

        // acc[it][c]: same 4-chain split + k-order as v3 (bit-identical logits)
        float acc[4][4];
        #pragma unroll
        for (int it = 0; it < 4; ++it)
            #pragma unroll
            for (int c = 0; c < 4; ++c) acc[it][c] = 0.f;

        #pragma unroll
        for (int j = 0; j < 8; ++j) {
            const int k = j * 128;
            f32x4 w0 = *(const f32x4*)(wr + k);
            f32x4 w1 = *(const f32x4*)(wr + k + 32);
            f32x4 w2 = *(const f32x4*)(wr + k + 64);
            f32x4 w3 = *(const f32x4*)(wr + k + 96);
            #pragma unroll
            for (int it = 0; it < 4; ++it) {
                f32x4 x0 = *(const f32x4*)(xr[it] + k);
                f32x4 x1 = *(const f32x4*)(xr[it] + k + 32);
                f32x4 x2 = *(const f32x4*)(xr[it] + k + 64);
                f32x4 x3 = *(const f32x4*)(xr[it] + k + 96);
                #pragma unroll
                for (int q = 0; q < 4; ++q) {
                    acc[it][0] = fmaf(w0[q], x0[q], acc[it][0]);
                    acc[it][1] = fmaf(w1[q], x1[q], acc[it][1]);
                    acc[it][2] = fmaf(w2[q], x2[q], acc[it][2]);
                    acc[it][3] = fmaf(w3[q], x3[q], acc[it][3]);
                }
            }
        }

        float bgl[NE];
        #pragma unroll
        for (int e = 0; e < NE; ++e) bgl[e] = bg[e];

        float mgacc = 0.f;
        #pragma unroll
        for (int it = 0; it < 4; ++it) {
            float a = (acc[it][0] + acc[it][1]) + (acc[it][2] + acc[it][3]);
            a += __shfl_xor(a, 1, 64);
            a += __shfl_xor(a, 2, 64);
            a += __shfl_xor(a, 4, 64);

            float logit[NE];
            #pragma unroll
            for (int e = 0; e < NE; ++e)
                logit[e] = __shfl(a, e * 8, 64) + bgl[e];

            float m = logit[0]; int am = 0;
            #pragma unroll
            for (int e = 1; e < NE; ++e) if (logit[e] > m) { m = logit[e]; am = e; }

            float p[NE], s = 0.f;
            #pragma unroll
            for (int e = 0; e < NE; ++e) { p[e] = __expf(logit[e] - m); s += p[e]; }
            const float inv = 1.f / s;

            float psel = p[0];
            #pragma unroll
            for (int e = 1; e < NE; ++e) psel = (lane == e) ? p[e] : psel;
            if (lane < NE) mgacc += psel * inv;

            if (lane == 0) sm.gt.am[wave * 4 + it] = am;
        }

        if (lane < NE) sm.gt.mg[wave][lane] = mgacc;
        __syncthreads();

        u32* rec = stage + (size_t)bid * 16;
        if (tid == 0) {
            u64 pack = 0;
            #pragma unroll
            for (int i = 0; i < 16; ++i) pack |= (u64)sm.gt.am[i] << (4 * i);
            *(u64*)rec = pack;
        }
        if (tid < NE) {
            float s = sm.gt.mg[0][tid] + sm.gt.mg[1][tid]
                    + sm.gt.mg[2][tid] + sm.gt.mg[3][tid];
            rec[2 + tid] = __float_as_uint(s);
        }
    }

    // ---------------- last-block election (device-scope) -------------------
    __threadfence();        // all threads: release this block's stage writes
    __syncthreads();
    if (tid == 0) {
        int old = __hip_atomic_fetch_add(done, 1, __ATOMIC_ACQ_REL,
                                         __HIP_MEMORY_SCOPE_AGENT);
        isLast = (old == 511);
    }
    __syncthreads();
    if (!isLast) return;
    __threadfence();        // acquire: invalidate stale cached stage lines

    // ---------------- route (elected block, 256 thr, 2 recs/thr) -----------
    {
        u64 pk[2];
        float mgr[NE];
        #pragma unroll
        for (int e = 0; e < NE; ++e) mgr[e] = 0.f;
        #pragma unroll
        for (int r = 0; r < 2; ++r) {
            const u32* rec = stage + (size_t)(2 * tid + r) * 16;
            pk[r] = *(const u64*)rec;
            #pragma unroll
            for (int e = 0; e < NE; ++e) mgr[e] += __uint_as_float(rec[2 + e]);
        }
        __syncthreads();    // everyone loaded before cnt overwrites union
        #pragma unroll
        for (int r = 0; r < 2; ++r) {
            int c8[NE];
            #pragma unroll
            for (int e = 0; e < NE; ++e) c8[e] = 0;
            #pragma unroll
            for (int it = 0; it < 16; ++it) c8[(int)((pk[r] >> (4 * it)) & 7)]++;
            #pragma unroll
            for (int e = 0; e < NE; ++e) sm.r.cnt[2 * tid + r][e] = c8[e];
        }
        __syncthreads();

        // exclusive scan over 512 records; wave w handles experts w, w+4
        #pragma unroll
        for (int half = 0; half < 2; ++half) {
            const int e = wave + 4 * half;
            int carry = 0;
            #pragma unroll 1
            for (int chn = 0; chn < 8; ++chn) {
                int v = sm.r.cnt[chn * 64 + lane][e];
                int incl = v;
                #pragma unroll
                for (int off = 1; off < 64; off <<= 1) {
                    int nn = __shfl_up(incl, off, 64);
                    if (lane >= off) incl += nn;
                }
                sm.r.cnt[chn * 64 + lane][e] = incl - v + carry;
                carry += __shfl(incl, 63, 64);
            }
            if (lane == 0) counts[e] = carry;
        }
        __syncthreads();

        // scatter (records pre-loaded; safe to overwrite stage region)
        #pragma unroll
        for (int r = 0; r < 2; ++r) {
            const int rec = 2 * tid + r;
            #pragma unroll
            for (int it = 0; it < 16; ++it) {
                int e3 = (int)((pk[r] >> (4 * it)) & 7);
                int pos = sm.r.cnt[rec][e3]++;
                tok_list[e3 * NTOK + pos] = rec * 16 + it;
            }
        }

        // mean-gate totals + aux
        #pragma unroll
        for (int e = 0; e < NE; ++e)
            #pragma unroll
            for (int off = 32; off > 0; off >>= 1)
                mgr[e] += __shfl_xor(mgr[e], off, 64);
        if (lane == 0)
            #pragma unroll
            for (int e = 0; e < NE; ++e) sm.r.mgred[wave][e] = mgr[e];
        __syncthreads();
        if (tid == 0) {
            float s = 0.f;
            #pragma unroll
            for (int e = 0; e < NE; ++e) {
                float m = (sm.r.mgred[0][e] + sm.r.mgred[1][e]
                         + sm.r.mgred[2][e] + sm.r.mgred[3][e]) * (8.0f / 8192.0f);
                s += m * m;
            }
            out[(size_t)NTOK * DOUT] = s * 0.125f;
        }
    }
}

// ---------------------------------------------------------------------------
// grouped GEMM (v7 verbatim, verified 76us / 0 bank conflicts):
// 64x128 tile, BK=64, 4 waves each 64x32 (4x2 of 16x16x32).
// LDS: bf16 sA[64][64] (8KB) + sB[128][64] (16KB), single-buffered.
// XOR-swizzled chunks (cx = ch ^ (row&7); rows 128B) on write and read.
// Schedule: barrier / write(k) / issue loads(k+1) / barrier / compute(k).
// Grid dim3(8 n, 128 m, 8 e): ~1088 active blocks = 4.25/CU.
// ---------------------------------------------------------------------------
__global__ __launch_bounds__(256) void moe_gemm(
    const float* __restrict__ x, const float* __restrict__ We,
    const float* __restrict__ be, const int* __restrict__ counts,
    const int* __restrict__ tok_list, float* __restrict__ out)
{
    const int e   = blockIdx.z;
    const int cnt = counts[e];
    const int m0  = blockIdx.y * 64;
    if (m0 >= cnt) return;
    const int n0  = blockIdx.x * 128;

    __shared__ u16 sA[64 * 64];    // 8 KB
    __shared__ u16 sB[128 * 64];   // 16 KB
    __shared__ int toks[64];

    const int tid = threadIdx.x;
    if (tid < 64) {
        int gr = m0 + tid;
        toks[tid] = (gr < cnt) ? tok_list[e * NTOK + gr] : tok_list[e * NTOK];
    }
    __syncthreads();

    const int lane = tid & 63;
    const int wave = tid >> 6;
    const int wn   = wave * 32;
    const int lrow = lane & 15;
    const int quad = lane >> 4;
    const int l7   = lrow & 7;

    f32x4 acc[4][2];
    #pragma unroll
    for (int i = 0; i < 4; ++i)
        #pragma unroll
        for (int j = 0; j < 2; ++j) acc[i][j] = (f32x4){0.f, 0.f, 0.f, 0.f};

    const int srow = tid >> 3;
    const int ch   = tid & 7;
    const int cx   = ch ^ (srow & 7);

    const float* aS[2];
    const float* bS[4];
    #pragma unroll
    for (int s = 0; s < 2; ++s)
        aS[s] = x + (size_t)toks[srow + 32 * s] * DIN + ch * 8;
    #pragma unroll
    for (int s = 0; s < 4; ++s)
        bS[s] = We + ((size_t)e << 20) + ((size_t)(n0 + srow + 32 * s) << 10) + ch * 8;

    f32x4 ar[2][2], br[4][2];

    #define LOADR(k0)                                            \
        do {                                                     \
            _Pragma("unroll")                                    \
            for (int s = 0; s < 2; ++s) {                        \
                ar[s][0] = *(const f32x4*)(aS[s] + (k0));        \
                ar[s][1] = *(const f32x4*)(aS[s] + (k0) + 4);    \
            }                                                    \
            _Pragma("unroll")                                    \
            for (int s = 0; s < 4; ++s) {                        \
                br[s][0] = *(const f32x4*)(bS[s] + (k0));        \
                br[s][1] = *(const f32x4*)(bS[s] + (k0) + 4);    \
            }                                                    \
        } while (0)

    #define STOREW()                                                     \
        do {                                                             \
            _Pragma("unroll")                                            \
            for (int s = 0; s < 2; ++s) {                                \
                union { u16 h[8]; uint4 u; } ua;                         \
                _Pragma("unroll")                                        \
                for (int q = 0; q < 4; ++q) {                            \
                    ua.h[q]     = f2bf(ar[s][0][q]);                     \
                    ua.h[4 + q] = f2bf(ar[s][1][q]);                     \
                }                                                        \
                *(uint4*)&sA[(srow + 32 * s) * 64 + cx * 8] = ua.u;      \
            }                                                            \
            _Pragma("unroll")                                            \
            for (int s = 0; s < 4; ++s) {                                \
                union { u16 h[8]; uint4 u; } ub;                         \
                _Pragma("unroll")                                        \
                for (int q = 0; q < 4; ++q) {                            \
                    ub.h[q]     = f2bf(br[s][0][q]);                     \
                    ub.h[4 + q] = f2bf(br[s][1][q]);                     \
                }                                                        \
                *(uint4*)&sB[(srow + 32 * s) * 64 + cx * 8] = ub.u;      \
            }                                                            \
        } while (0)

    #define COMPUTE()                                                         \
        do {                                                                  \
            bf16x8 af[2][4], bv[2][2];                                        \
            _Pragma("unroll")                                                 \
            for (int ks = 0; ks < 2; ++ks) {                                  \
                const int so = ((ks * 4 + quad) ^ l7) * 8;                    \
                _Pragma("unroll")                                             \
                for (int i = 0; i < 4; ++i)                                   \
                    af[ks][i] = *(const bf16x8*)&sA[(i * 16 + lrow) * 64 + so]; \
                _Pragma("unroll")                                             \
                for (int j = 0; j < 2; ++j)                                   \
                    bv[ks][j] = *(const bf16x8*)&sB[(wn + j * 16 + lrow) * 64 + so]; \
            }                                                                 \
            _Pragma("unroll")                                                 \
            for (int ks = 0; ks < 2; ++ks)                                    \
                _Pragma("unroll")                                             \
                for (int i = 0; i < 4; ++i)                                   \
                    _Pragma("unroll")                                         \
                    for (int j = 0; j < 2; ++j)                               \
                        acc[i][j] = __builtin_amdgcn_mfma_f32_16x16x32_bf16(  \
                            af[ks][i], bv[ks][j], acc[i][j], 0, 0, 0);        \
        } while (0)

    LOADR(0);
    #pragma unroll 1
    for (int k0 = 0; k0 < DIN; k0 += 64) {
        __syncthreads();
        STOREW();
        if (k0 + 64 < DIN) LOADR(k0 + 64);
        __syncthreads();
        COMPUTE();
    }

    #undef LOADR
    #undef STOREW
    #undef COMPUTE

    #pragma unroll
    for (int j = 0; j < 2; ++j) {
        const int col = n0 + wn + j * 16 + lrow;
        const float bev = be[e * DOUT + col];
        #pragma unroll
        for (int i = 0; i < 4; ++i) {
            #pragma unroll
            for (int r = 0; r < 4; ++r) {
                const int rl = i * 16 + quad * 4 + r;
                if (m0 + rl < cnt) {
                    const int tok = toks[rl];
                    out[((size_t)tok << 10) + col] = acc[i][j][r] + bev;
                }
            }
        }
    }
}

extern "C" void kernel_launch(void* const* d_in, const int* in_sizes, int n_in,
                              void* d_out, int out_size, void* d_ws, size_t ws_size,
                              hipStream_t stream) {
    const float* x  = (const float*)d_in[0];
    const float* We = (const float*)d_in[1];
    const float* be = (const float*)d_in[2];
    const float* Wg = (const float*)d_in[3];
    const float* bg = (const float*)d_in[4];
    float* out = (float*)d_out;

    int* counts   = (int*)d_ws;
    int* done     = (int*)((char*)d_ws + 32);
    int* tok_list = (int*)((char*)d_ws + 256);
    u32* stage    = (u32*)((char*)d_ws + 256);

    hipMemsetAsync(d_ws, 0, 64, stream);   // zero counts + done ticket
    gate_route_kernel<<<512, 256, 0, stream>>>(x, Wg, bg, counts, done,
                                               tok_list, stage, out);
    moe_gemm<<<dim3(8, 128, 8), 256, 0, stream>>>(x, We, be, counts, tok_list, out);
}

// Round 9
// 233.524 us; speedup vs baseline: 1.0656x; 1.0656x over previous
//
#include <hip/hip_runtime.h>
#include <hip/hip_bf16.h>

// SwitchLinear: B=4,S=2048,D_IN=1024,D_OUT=1024,E=8
// Established contract: ALL inputs fp32, OUTPUT fp32 (out_size=8388609 floats:
// 8192x1024 dense out + aux scalar). ws >= 262400 B. Routing = argmax of fp32
// gate logits; out[t,:] = x[t]@We[top1]^T + be[top1]; aux = mean((mean_gate*E)^2).
// Value GEMM: bf16 MFMA (~1e-3 error << 6.4e-2 threshold). Gate logits fp32.
//
// v10: gate rebuilt as LDS-staged streaming kernel. Diagnosis (r8): gate has
// been 60-100us in EVERY round (r8 finally showed it: 88us, VGPR=256 from the
// v9 ILP unroll). Root cause: per-lane-group x reads touch only 128 distinct
// B per VMEM instr (8x duplication) + fp32 rows can't live in registers.
// Now: 512 blocks x 128 thr, thread=(token,expert); per BK=64 chunk stage
// x[16][64] coalesced (16B/lane contiguous), reg-prefetch next chunk, compute
// from LDS (rows padded to 68 floats -> conflict-free b128), Wg from global
// (32KB, L1-resident). 8-lane shuffle-tree argmax (first-max-wins). Record
// format unchanged (block=record). v9's verified last-block route fusion kept
// (128-thr relane, 4 recs/thread). gemm = v7 verbatim (76us, 0 conflicts).

#define NTOK 8192
#define DIN  1024
#define DOUT 1024
#define NE   8

typedef unsigned short u16;
typedef unsigned int   u32;
typedef unsigned long long u64;
typedef short  bf16x8 __attribute__((ext_vector_type(8)));
typedef float  f32x4  __attribute__((ext_vector_type(4)));

__device__ __forceinline__ u16 f2bf(float f) {
    __hip_bfloat16 h = __float2bfloat16(f);   // RNE
    return *(u16*)&h;
}

// ws layout: [0,32) counts[8] | [32,36) done | [256, 262400) tok_list[8][8192]
// First 32KB of tok_list region doubles as gate-record staging (512 x 64B);
// route loads ALL records before the scatter overwrites them.

// ---------------------------------------------------------------------------
// gate+route: 512 blocks x 128 thr; block = 16 tokens = 1 record.
// Thread = (token itok = tid>>3, expert e = tid&7).
// ---------------------------------------------------------------------------
__global__ __launch_bounds__(128) void gate_route_kernel(
    const float* __restrict__ x, const float* __restrict__ Wg,
    const float* __restrict__ bg, int* __restrict__ counts,
    int* __restrict__ done, int* __restrict__ tok_list,
    u32* __restrict__ stage, float* __restrict__ out)
{
    __shared__ union {
        struct { float xs[16 * 68]; int am[16]; float mg[2][NE]; } g; // 4.5 KB
        struct { int cnt[512][9]; float mgred[2][NE]; } r;            // 18.5 KB
    } sm;
    __shared__ int isLast;

    const int tid  = threadIdx.x;
    const int bid  = blockIdx.x;
    const int wave = tid >> 6;
    const int lane = tid & 63;
    const int itok = tid >> 3;          // 0..15
    const int e    = tid & 7;

    // ------------------------------ gate -----------------------------------
    {
        // staging map: thread stages 32B of row itok at float col (tid&7)*8
        const int scolf = (tid & 7) * 8;
        const float* xsrc = x + (size_t)(bid * 16 + itok) * DIN + scolf;
        const float* wp   = Wg + e * DIN;

        float acc[4] = {0.f, 0.f, 0.f, 0.f};
        f32x4 r0, r1;

        r0 = *(const f32x4*)(xsrc);           // prefetch chunk 0
        r1 = *(const f32x4*)(xsrc + 4);

        #pragma unroll 1
        for (int c = 0; c < 16; ++c) {
            const int kb = c * 64;
            __syncthreads();                  // prev compute done reading
            *(f32x4*)&sm.g.xs[itok * 68 + scolf]     = r0;
            *(f32x4*)&sm.g.xs[itok * 68 + scolf + 4] = r1;
            if (c < 15) {                     // prefetch next chunk
                r0 = *(const f32x4*)(xsrc + kb + 64);
                r1 = *(const f32x4*)(xsrc + kb + 68);
            }
            __syncthreads();                  // tile visible
            #pragma unroll
            for (int kl4 = 0; kl4 < 16; ++kl4) {
                f32x4 xv = *(const f32x4*)&sm.g.xs[itok * 68 + kl4 * 4];
                f32x4 wv = *(const f32x4*)(wp + kb + kl4 * 4);
                #pragma unroll
                for (int q = 0; q < 4; ++q)
                    acc[kl4 & 3] = fmaf(wv[q], xv[q], acc[kl4 & 3]);
            }
        }

        const float logit = (acc[0] + acc[1]) + (acc[2] + acc[3]) + bg[e];

        // 8-lane argmax tree, first-max-wins (== np linear scan)
        float v = logit; int ix = e;
        #pragma unroll
        for (int off = 1; off < 8; off <<= 1) {
            float pv = __shfl_xor(v, off, 64);
            int  pix = __shfl_xor(ix, off, 64);
            if (pv > v || (pv == v && pix < ix)) { v = pv; ix = pix; }
        }

        float p = __expf(logit - v);
        float ssum = p;
        #pragma unroll
        for (int off = 1; off < 8; off <<= 1) ssum += __shfl_xor(ssum, off, 64);
        float mgval = p * (1.f / ssum);

        // sum mgval across the wave's 8 tokens (lanes stride 8, same e)
        #pragma unroll
        for (int off = 8; off < 64; off <<= 1) mgval += __shfl_xor(mgval, off, 64);

        if (e == 0) sm.g.am[itok] = ix;
        if (lane < NE) sm.g.mg[wave][lane] = mgval;
        __syncthreads();

        u32* rec = stage + (size_t)bid * 16;
        if (tid == 0) {
            u64 pack = 0;
            #pragma unroll
            for (int i = 0; i < 16; ++i) pack |= (u64)sm.g.am[i] << (4 * i);
            *(u64*)rec = pack;
        }
        if (tid < NE)
            rec[2 + tid] = __float_as_uint(sm.g.mg[0][tid] + sm.g.mg[1][tid]);
    }

    // ---------------- last-block election (device-scope) -------------------
    __threadfence();
    __syncthreads();
    if (tid == 0) {
        int old = __hip_atomic_fetch_add(done, 1, __ATOMIC_ACQ_REL,
                                         __HIP_MEMORY_SCOPE_AGENT);
        isLast = (old == 511);
    }
    __syncthreads();
    if (!isLast) return;
    __threadfence();

    // ---------------- route (elected block, 128 thr, 4 recs/thr) -----------
    {
        u64 pk[4];
        float mgr[NE];
        #pragma unroll
        for (int q = 0; q < NE; ++q) mgr[q] = 0.f;
        #pragma unroll
        for (int j = 0; j < 4; ++j) {
            const u32* rec = stage + (size_t)(4 * tid + j) * 16;
            pk[j] = *(const u64*)rec;
            #pragma unroll
            for (int q = 0; q < NE; ++q) mgr[q] += __uint_as_float(rec[2 + q]);
        }
        __syncthreads();    // all record loads done before union overwrite
        #pragma unroll
        for (int j = 0; j < 4; ++j) {
            int c8[NE];
            #pragma unroll
            for (int q = 0; q < NE; ++q) c8[q] = 0;
            #pragma unroll
            for (int it = 0; it < 16; ++it) c8[(int)((pk[j] >> (4 * it)) & 7)]++;
            #pragma unroll
            for (int q = 0; q < NE; ++q) sm.r.cnt[4 * tid + j][q] = c8[q];
        }
        __syncthreads();

        // exclusive scan over 512 records; wave w handles experts 4w..4w+3
        #pragma unroll
        for (int q = 0; q < 4; ++q) {
            const int ee = wave * 4 + q;
            int carry = 0;
            #pragma unroll 1
            for (int chn = 0; chn < 8; ++chn) {
                int vv = sm.r.cnt[chn * 64 + lane][ee];
                int incl = vv;
                #pragma unroll
                for (int off = 1; off < 64; off <<= 1) {
                    int nn = __shfl_up(incl, off, 64);
                    if (lane >= off) incl += nn;
                }
                sm.r.cnt[chn * 64 + lane][ee] = incl - vv + carry;
                carry += __shfl(incl, 63, 64);
            }
            if (lane == 0) counts[ee] = carry;
        }
        __syncthreads();

        // scatter (records pre-loaded; safe to overwrite stage region)
        #pragma unroll
        for (int j = 0; j < 4; ++j) {
            const int rec = 4 * tid + j;
            #pragma unroll
            for (int it = 0; it < 16; ++it) {
                int e3 = (int)((pk[j] >> (4 * it)) & 7);
                int pos = sm.r.cnt[rec][e3]++;
                tok_list[e3 * NTOK + pos] = rec * 16 + it;
            }
        }

        // mean-gate totals + aux
        #pragma unroll
        for (int q = 0; q < NE; ++q)
            #pragma unroll
            for (int off = 32; off > 0; off >>= 1)
                mgr[q] += __shfl_xor(mgr[q], off, 64);
        if (lane == 0)
            #pragma unroll
            for (int q = 0; q < NE; ++q) sm.r.mgred[wave][q] = mgr[q];
        __syncthreads();
        if (tid == 0) {
            float s = 0.f;
            #pragma unroll
            for (int q = 0; q < NE; ++q) {
                float m = (sm.r.mgred[0][q] + sm.r.mgred[1][q]) * (8.0f / 8192.0f);
                s += m * m;
            }
            out[(size_t)NTOK * DOUT] = s * 0.125f;
        }
    }
}

// ---------------------------------------------------------------------------
// grouped GEMM (v7 verbatim, verified 76us / 0 bank conflicts):
// 64x128 tile, BK=64, 4 waves each 64x32 (4x2 of 16x16x32).
// LDS: bf16 sA[64][64] (8KB) + sB[128][64] (16KB), single-buffered.
// XOR-swizzled chunks (cx = ch ^ (row&7); rows 128B) on write and read.
// Schedule: barrier / write(k) / issue loads(k+1) / barrier / compute(k).
// Grid dim3(8 n, 128 m, 8 e): ~1088 active blocks = 4.25/CU.
// ---------------------------------------------------------------------------
__global__ __launch_bounds__(256) void moe_gemm(
    const float* __restrict__ x, const float* __restrict__ We,
    const float* __restrict__ be, const int* __restrict__ counts,
    const int* __restrict__ tok_list, float* __restrict__ out)
{
    const int e   = blockIdx.z;
    const int cnt = counts[e];
    const int m0  = blockIdx.y * 64;
    if (m0 >= cnt) return;
    const int n0  = blockIdx.x * 128;

    __shared__ u16 sA[64 * 64];    // 8 KB
    __shared__ u16 sB[128 * 64];   // 16 KB
    __shared__ int toks[64];

    const int tid = threadIdx.x;
    if (tid < 64) {
        int gr = m0 + tid;
        toks[tid] = (gr < cnt) ? tok_list[e * NTOK + gr] : tok_list[e * NTOK];
    }
    __syncthreads();

    const int lane = tid & 63;
    const int wave = tid >> 6;
    const int wn   = wave * 32;
    const int lrow = lane & 15;
    const int quad = lane >> 4;
    const int l7   = lrow & 7;

    f32x4 acc[4][2];
    #pragma unroll
    for (int i = 0; i < 4; ++i)
        #pragma unroll
        for (int j = 0; j < 2; ++j) acc[i][j] = (f32x4){0.f, 0.f, 0.f, 0.f};

    const int srow = tid >> 3;
    const int ch   = tid & 7;
    const int cx   = ch ^ (srow & 7);

    const float* aS[2];
    const float* bS[4];
    #pragma unroll
    for (int s = 0; s < 2; ++s)
        aS[s] = x + (size_t)toks[srow + 32 * s] * DIN + ch * 8;
    #pragma unroll
    for (int s = 0; s < 4; ++s)
        bS[s] = We + ((size_t)e << 20) + ((size_t)(n0 + srow + 32 * s) << 10) + ch * 8;

    f32x4 ar[2][2], br[4][2];

    #define LOADR(k0)                                            \
        do {                                                     \
            _Pragma("unroll")                                    \
            for (int s = 0; s < 2; ++s) {                        \
                ar[s][0] = *(const f32x4*)(aS[s] + (k0));        \
                ar[s][1] = *(const f32x4*)(aS[s] + (k0) + 4);    \
            }                                                    \
            _Pragma("unroll")                                    \
            for (int s = 0; s < 4; ++s) {                        \
                br[s][0] = *(const f32x4*)(bS[s] + (k0));        \
                br[s][1] = *(const f32x4*)(bS[s] + (k0) + 4);    \
            }                                                    \
        } while (0)

    #define STOREW()                                                     \
        do {                                                             \
            _Pragma("unroll")                                            \
            for (int s = 0; s < 2; ++s) {                                \
                union { u16 h[8]; uint4 u; } ua;                         \
                _Pragma("unroll")                                        \
                for (int q = 0; q < 4; ++q) {                            \
                    ua.h[q]     = f2bf(ar[s][0][q]);                     \
                    ua.h[4 + q] = f2bf(ar[s][1][q]);                     \
                }                                                        \
                *(uint4*)&sA[(srow + 32 * s) * 64 + cx * 8] = ua.u;      \
            }                                                            \
            _Pragma("unroll")                                            \
            for (int s = 0; s < 4; ++s) {                                \
                union { u16 h[8]; uint4 u; } ub;                         \
                _Pragma("unroll")                                        \
                for (int q = 0; q < 4; ++q) {                            \
                    ub.h[q]     = f2bf(br[s][0][q]);                     \
                    ub.h[4 + q] = f2bf(br[s][1][q]);                     \
                }                                                        \
                *(uint4*)&sB[(srow + 32 * s) * 64 + cx * 8] = ub.u;      \
            }                                                            \
        } while (0)

    #define COMPUTE()                                                         \
        do {                                                                  \
            bf16x8 af[2][4], bv[2][2];                                        \
            _Pragma("unroll")                                                 \
            for (int ks = 0; ks < 2; ++ks) {                                  \
                const int so = ((ks * 4 + quad) ^ l7) * 8;                    \
                _Pragma("unroll")                                             \
                for (int i = 0; i < 4; ++i)                                   \
                    af[ks][i] = *(const bf16x8*)&sA[(i * 16 + lrow) * 64 + so]; \
                _Pragma("unroll")                                             \
                for (int j = 0; j < 2; ++j)                                   \
                    bv[ks][j] = *(const bf16x8*)&sB[(wn + j * 16 + lrow) * 64 + so]; \
            }                                                                 \
            _Pragma("unroll")                                                 \
            for (int ks = 0; ks < 2; ++ks)                                    \
                _Pragma("unroll")                                             \
                for (int i = 0; i < 4; ++i)                                   \
                    _Pragma("unroll")                                         \
                    for (int j = 0; j < 2; ++j)                               \
                        acc[i][j] = __builtin_amdgcn_mfma_f32_16x16x32_bf16(  \
                            af[ks][i], bv[ks][j], acc[i][j], 0, 0, 0);        \
        } while (0)

    LOADR(0);
    #pragma unroll 1
    for (int k0 = 0; k0 < DIN; k0 += 64) {
        __syncthreads();
        STOREW();
        if (k0 + 64 < DIN) LOADR(k0 + 64);
        __syncthreads();
        COMPUTE();
    }

    #undef LOADR
    #undef STOREW
    #undef COMPUTE

    #pragma unroll
    for (int j = 0; j < 2; ++j) {
        const int col = n0 + wn + j * 16 + lrow;
        const float bev = be[e * DOUT + col];
        #pragma unroll
        for (int i = 0; i < 4; ++i) {
            #pragma unroll
            for (int r = 0; r < 4; ++r) {
                const int rl = i * 16 + quad * 4 + r;
                if (m0 + rl < cnt) {
                    const int tok = toks[rl];
                    out[((size_t)tok << 10) + col] = acc[i][j][r] + bev;
                }
            }
        }
    }
}

extern "C" void kernel_launch(void* const* d_in, const int* in_sizes, int n_in,
                              void* d_out, int out_size, void* d_ws, size_t ws_size,
                              hipStream_t stream) {
    const float* x  = (const float*)d_in[0];
    const float* We = (const float*)d_in[1];
    const float* be = (const float*)d_in[2];
    const float* Wg = (const float*)d_in[3];
    const float* bg = (const float*)d_in[4];
    float* out = (float*)d_out;

    int* counts   = (int*)d_ws;
    int* done     = (int*)((char*)d_ws + 32);
    int* tok_list = (int*)((char*)d_ws + 256);
    u32* stage    = (u32*)((char*)d_ws + 256);

    hipMemsetAsync(d_ws, 0, 64, stream);   // zero counts + done ticket
    gate_route_kernel<<<512, 128, 0, stream>>>(x, Wg, bg, counts, done,
                                               tok_list, stage, out);
    moe_gemm<<<dim3(8, 128, 8), 256, 0, stream>>>(x, We, be, counts, tok_list, out);
}